// Round 9
// baseline (375.007 us; speedup 1.0000x reference)
//
#include <hip/hip_runtime.h>
#include <hip/hip_bf16.h>
#include <math.h>
#include <stdint.h>

#define LDD 4096
#define LEE 8192
#define CDIM 512
#define CENC 256
#define HDIM 2048
#define NB 4
#define NHEAD 8
#define HD 64
#define NWIN 22
#define WINQ 256
#define WSTRIDE 192

typedef __attribute__((ext_vector_type(8))) short bf16x8;
typedef __attribute__((ext_vector_type(8))) unsigned short u16x8;
typedef __attribute__((ext_vector_type(4))) float f32x4;
typedef __attribute__((ext_vector_type(16))) float f32x16;
typedef __attribute__((ext_vector_type(2))) unsigned int u32x2;
typedef __attribute__((ext_vector_type(4))) unsigned int u32x4;
typedef unsigned short ushort_t;

__device__ __forceinline__ uint32_t pack2(float lo, float hi) {
    return ((__float_as_uint(hi) + 0x8000u) & 0xffff0000u) |
           ((__float_as_uint(lo) + 0x8000u) >> 16);
}
__device__ __forceinline__ ushort_t bfc(float x) {
    return (ushort_t)((__float_as_uint(x) + 0x8000u) >> 16);
}
__device__ __forceinline__ float bf2f(ushort_t u) {
    return __uint_as_float(((uint32_t)u) << 16);
}
__device__ __forceinline__ void gload16(const void* g, void* l) {
    __builtin_amdgcn_global_load_lds(
        (const __attribute__((address_space(1))) void*)g,
        (__attribute__((address_space(3))) void*)l, 16, 0, 0);
}
// fast erf-based gelu (A&S 7.1.26, |eps| <= 1.5e-7)
__device__ __forceinline__ float gelu_fast(float x) {
    float z = fabsf(x) * 0.70710678f;
    float t = 1.0f / fmaf(0.3275911f, z, 1.0f);
    float p = t * fmaf(t, fmaf(t, fmaf(t, fmaf(t, 1.061405429f, -1.453152027f),
                                        1.421413741f), -0.284496736f), 0.254829592f);
    float e = __expf(-z * z);
    float erfz = fmaf(-p, e, 1.0f);
    float sgn = copysignf(erfz, x);
    return 0.5f * x * (1.0f + sgn);
}

// ---------------------------------------------------------------------------
// Weights f32 -> bf16, 6 segments in one launch. grid (1024, 6).
// ---------------------------------------------------------------------------
struct Cvt6Args {
    const float* src[6];
    ushort_t* dst[6];
    int n[6];
};
__global__ __launch_bounds__(256)
void cvt6(Cvt6Args a)
{
    int seg = blockIdx.y;
    int i = (blockIdx.x * 256 + threadIdx.x) * 4;
    if (i < a.n[seg]) {
        float4 v = *reinterpret_cast<const float4*>(&a.src[seg][i]);
        u32x2 p; p[0] = pack2(v.x, v.y); p[1] = pack2(v.z, v.w);
        *reinterpret_cast<u32x2*>(&a.dst[seg][i]) = p;
    }
}

// ---------------------------------------------------------------------------
// Transpose+convert: f32 [B][C][L] -> bf16 [B][L][C]. grid (L/64, C/64, B)
// ---------------------------------------------------------------------------
__global__ __launch_bounds__(256)
void tcvt(const float* __restrict__ in, ushort_t* __restrict__ outb, int C, int L)
{
    __shared__ float T[64][65];
    int l0 = blockIdx.x * 64, c0 = blockIdx.y * 64, b = blockIdx.z;
    int tid = threadIdx.x;
    int ll = tid & 63, cq = tid >> 6;
    #pragma unroll
    for (int i = 0; i < 16; ++i) {
        int c = cq + i * 4;
        T[c][ll] = in[((size_t)b * C + c0 + c) * L + l0 + ll];
    }
    __syncthreads();
    int cc = tid & 63, lq = tid >> 6;
    #pragma unroll
    for (int i = 0; i < 16; ++i) {
        int l = lq + i * 4;
        outb[((size_t)b * L + l0 + l) * C + c0 + cc] = bfc(T[cc][l]);
    }
}

// ---------------------------------------------------------------------------
// MFMA GEMM mgemm256: 256x256 tile, BK=64, 8 waves (2m x 4n, per-wave
// 128x64), 2-buffer LDS, proven 2-phase __syncthreads schedule (mgemm2's,
// bigger tile: 64 MFMA per barrier instead of 32).
// Out[b][m][n] = ep(sum_k A[m][k]W[n][k]+bias[n]). grid (N/256, M/256, B).
// ---------------------------------------------------------------------------
template<int EPI, int STATS>
__global__ __launch_bounds__(512, 2)
void mgemm256(const ushort_t* __restrict__ A, const ushort_t* __restrict__ Wt,
              const float* __restrict__ bias, ushort_t* __restrict__ Out,
              float* __restrict__ part, int M, int N, int K)
{
    __shared__ __align__(16) ushort_t As[2][16384];   // 256 rows x 64 k per buf
    __shared__ __align__(16) ushort_t Bs[2][16384];   // 256 rows x 64 k per buf

    int Nt = gridDim.x;
    int flat = blockIdx.y * Nt + blockIdx.x;
    int nwg = Nt * gridDim.y;
    int swz = (flat & 7) * (nwg >> 3) + (flat >> 3);   // nwg % 8 == 0 all shapes
    int nb = swz % Nt, mb = swz / Nt;
    int b = blockIdx.z;
    int m0 = mb * 256, n0 = nb * 256;

    int tid = threadIdx.x;
    int lane = tid & 63;
    int w = tid >> 6;                 // 0..7
    int q16 = lane & 15, g = lane >> 4;
    int wr = w >> 2, wc = w & 3;      // 2m x 4n wave grid

    // pre-swizzled per-lane global sources (linear LDS dest, inverse-swz src)
    const ushort_t* Ag[4]; const ushort_t* Wg[4];
    #pragma unroll
    for (int i = 0; i < 4; ++i) {
        int gran = w * 256 + i * 64 + lane;      // 0..2047 (16B granules)
        int row = gran >> 3;
        int c8 = (gran & 7) ^ (row & 7);
        Ag[i] = A + ((size_t)b * M + m0 + row) * K + c8 * 8;
        Wg[i] = Wt + ((size_t)(n0 + row)) * K + c8 * 8;
    }

    f32x4 acc[8][4];
    #pragma unroll
    for (int mt = 0; mt < 8; ++mt)
        #pragma unroll
        for (int nt = 0; nt < 4; ++nt) {
            acc[mt][nt][0] = 0.f; acc[mt][nt][1] = 0.f;
            acc[mt][nt][2] = 0.f; acc[mt][nt][3] = 0.f;
        }

    #pragma unroll
    for (int i = 0; i < 4; ++i) {
        gload16(Ag[i], &As[0][w * 2048 + i * 512]);
        gload16(Wg[i], &Bs[0][w * 2048 + i * 512]);
    }

    int NTILES = K >> 6;
    for (int kt = 0; kt < NTILES; ++kt) {
        int cur = kt & 1;
        __syncthreads();
        if (kt + 1 < NTILES) {
            int k0 = (kt + 1) << 6;
            #pragma unroll
            for (int i = 0; i < 4; ++i) {
                gload16(Ag[i] + k0, &As[cur ^ 1][w * 2048 + i * 512]);
                gload16(Wg[i] + k0, &Bs[cur ^ 1][w * 2048 + i * 512]);
            }
        }
        const char* Ab = (const char*)&As[cur][0];
        const char* Bb = (const char*)&Bs[cur][0];
        bf16x8 kb[4][2];
        #pragma unroll
        for (int nt = 0; nt < 4; ++nt) {
            int r = wc * 64 + nt * 16 + q16;
            int rb = r * 128;
            int sw8 = (r & 7) << 4;
            kb[nt][0] = *reinterpret_cast<const bf16x8*>(Bb + rb + ((g * 16) ^ sw8));
            kb[nt][1] = *reinterpret_cast<const bf16x8*>(Bb + rb + ((64 + g * 16) ^ sw8));
        }
        #pragma unroll
        for (int half = 0; half < 2; ++half) {
            bf16x8 ka[4][2];
            #pragma unroll
            for (int mt = 0; mt < 4; ++mt) {
                int r = wr * 128 + half * 64 + mt * 16 + q16;
                int rb = r * 128;
                int sw8 = (r & 7) << 4;
                ka[mt][0] = *reinterpret_cast<const bf16x8*>(Ab + rb + ((g * 16) ^ sw8));
                ka[mt][1] = *reinterpret_cast<const bf16x8*>(Ab + rb + ((64 + g * 16) ^ sw8));
            }
            #pragma unroll
            for (int mt = 0; mt < 4; ++mt)
                #pragma unroll
                for (int nt = 0; nt < 4; ++nt) {
                    acc[half * 4 + mt][nt] = __builtin_amdgcn_mfma_f32_16x16x32_bf16(kb[nt][0], ka[mt][0], acc[half * 4 + mt][nt], 0, 0, 0);
                    acc[half * 4 + mt][nt] = __builtin_amdgcn_mfma_f32_16x16x32_bf16(kb[nt][1], ka[mt][1], acc[half * 4 + mt][nt], 0, 0, 0);
                }
        }
    }

    // epilogue: D row=(g*4+reg) -> n, col=q16 -> m (operands swapped)
    float4 bv4[4];
    #pragma unroll
    for (int nt = 0; nt < 4; ++nt)
        bv4[nt] = *reinterpret_cast<const float4*>(&bias[n0 + wc * 64 + nt * 16 + g * 4]);

    float s_[4][4], q_[4][4];
    if (STATS) {
        #pragma unroll
        for (int nt = 0; nt < 4; ++nt)
            #pragma unroll
            for (int r = 0; r < 4; ++r) { s_[nt][r] = 0.f; q_[nt][r] = 0.f; }
    }

    #pragma unroll
    for (int mt = 0; mt < 8; ++mt) {
        int m = m0 + wr * 128 + mt * 16 + q16;
        size_t rowoff = ((size_t)b * M + m) * N;
        #pragma unroll
        for (int nt = 0; nt < 4; ++nt) {
            float vv[4];
            #pragma unroll
            for (int r = 0; r < 4; ++r) {
                float val = acc[mt][nt][r] + ((const float*)&bv4[nt])[r];
                if (EPI == 1) val = gelu_fast(val);
                if (STATS) { s_[nt][r] += val; q_[nt][r] = fmaf(val, val, q_[nt][r]); }
                vv[r] = val;
            }
            u32x2 pk; pk[0] = pack2(vv[0], vv[1]); pk[1] = pack2(vv[2], vv[3]);
            *reinterpret_cast<u32x2*>(&Out[rowoff + n0 + wc * 64 + nt * 16 + g * 4]) = pk;
        }
    }

    if (STATS) {
        __syncthreads();
        float* SS = (float*)&As[0][0];   // [256][33] floats = 33.8 KB (fits 64 KB)
        float* SQ = (float*)&Bs[0][0];
        #pragma unroll
        for (int nt = 0; nt < 4; ++nt)
            #pragma unroll
            for (int r = 0; r < 4; ++r) {
                int nl = wc * 64 + nt * 16 + g * 4 + r;     // 0..255
                SS[nl * 33 + wr * 16 + q16] = s_[nt][r];
                SQ[nl * 33 + wr * 16 + q16] = q_[nt][r];
            }
        __syncthreads();
        if (tid < 256) {
            float ts = 0.f, tq = 0.f;
            #pragma unroll 8
            for (int j = 0; j < 32; ++j) { ts += SS[tid * 33 + j]; tq += SQ[tid * 33 + j]; }
            size_t po = (((size_t)b * (M >> 8) + mb) * N + n0 + tid) * 2;
            part[po] = ts; part[po + 1] = tq;
        }
    }
}

// ---------------------------------------------------------------------------
// Finish per-channel stats for k and v: part[b][SPLIT][512][2] -> mean/rstd.
// ---------------------------------------------------------------------------
__global__ __launch_bounds__(256)
void stats_finish(const float* __restrict__ pk, const float* __restrict__ pv,
                  float* __restrict__ km, float* __restrict__ kr,
                  float* __restrict__ vm, float* __restrict__ vr, int SPLIT)
{
    int id = blockIdx.x * 256 + threadIdx.x;   // 0..2047
    int b = id >> 9, c = id & 511;
    float sk = 0.f, qk = 0.f, sv = 0.f, qv = 0.f;
    for (int sp = 0; sp < SPLIT; ++sp) {
        size_t po = (((size_t)(b * SPLIT + sp)) * CDIM + c) * 2;
        sk += pk[po]; qk += pk[po + 1];
        sv += pv[po]; qv += pv[po + 1];
    }
    float mk = sk / (float)LEE, mv = sv / (float)LEE;
    km[id] = mk;
    kr[id] = rsqrtf(qk / (float)LEE - mk * mk + 1e-5f);
    vm[id] = mv;
    vr[id] = rsqrtf(qv / (float)LEE - mv * mv + 1e-5f);
}

// ---------------------------------------------------------------------------
// Column-norm apply (vectorized, bf16 in/out, C=512). grid (L/16, 1, B).
// ---------------------------------------------------------------------------
template<int RES>
__global__ __launch_bounds__(256)
void cn_apply_v(const ushort_t* __restrict__ in, const float* __restrict__ part,
                const ushort_t* __restrict__ res, ushort_t* __restrict__ out,
                const float* __restrict__ chscale,
                int L, int SPLITM, float oscale)
{
    __shared__ float SM[CDIM], SR[CDIM];
    int b = blockIdx.z;
    int tid = threadIdx.x;
    for (int c = tid; c < CDIM; c += 256) {
        float fs = 0.f, fq = 0.f;
        for (int sp = 0; sp < SPLITM; ++sp) {
            size_t po = (((size_t)b * SPLITM + sp) * CDIM + c) * 2;
            fs += part[po]; fq += part[po + 1];
        }
        float mean = fs / (float)L;
        float var = fq / (float)L - mean * mean;
        float sc = oscale;
        if (chscale) sc *= chscale[b * CDIM + c];
        SM[c] = mean; SR[c] = rsqrtf(var + 1e-5f) * sc;
    }
    __syncthreads();
    int c0 = (tid & 63) * 8;
    int l0 = blockIdx.x * 16 + (tid >> 6) * 4;
    float mm[8], rr[8];
    #pragma unroll
    for (int j = 0; j < 8; ++j) { mm[j] = SM[c0 + j]; rr[j] = SR[c0 + j]; }
    #pragma unroll
    for (int i = 0; i < 4; ++i) {
        int l = l0 + i;
        size_t off = ((size_t)b * L + l) * CDIM + c0;
        u16x8 v = *reinterpret_cast<const u16x8*>(in + off);
        u16x8 rv;
        if (RES) rv = *reinterpret_cast<const u16x8*>(res + off);
        u16x8 o;
        #pragma unroll
        for (int j = 0; j < 8; ++j) {
            float y = (bf2f((ushort_t)v[j]) - mm[j]) * rr[j];
            if (RES) y += bf2f((ushort_t)rv[j]);
            o[j] = bfc(y);
        }
        *reinterpret_cast<u16x8*>(out + off) = o;
    }
}

// ---------------------------------------------------------------------------
// Final: out[B][C][L] f32 = norm(in)[l][c] + res[l][c], transposed write.
// ---------------------------------------------------------------------------
__global__ __launch_bounds__(256)
void cn_apply_t(const ushort_t* __restrict__ in, const float* __restrict__ part,
                const ushort_t* __restrict__ res, float* __restrict__ outf,
                int L, int SPLITM)
{
    __shared__ float SM[64], SR[64];
    __shared__ float T[64][65];
    int b = blockIdx.z;
    int c0 = blockIdx.x * 64;
    int l0 = blockIdx.y * 64;
    int tid = threadIdx.x;
    if (tid < 64) {
        int c = c0 + tid;
        float fs = 0.f, fq = 0.f;
        for (int sp = 0; sp < SPLITM; ++sp) {
            size_t po = (((size_t)b * SPLITM + sp) * CDIM + c) * 2;
            fs += part[po]; fq += part[po + 1];
        }
        float mean = fs / (float)L;
        float var = fq / (float)L - mean * mean;
        SM[tid] = mean; SR[tid] = rsqrtf(var + 1e-5f);
    }
    __syncthreads();
    int cc = tid & 63;
    int lq = tid >> 6;
    float mean = SM[cc], rstd = SR[cc];
    #pragma unroll
    for (int i = 0; i < 16; ++i) {
        int l = l0 + lq + i * 4;
        size_t idx = ((size_t)b * L + l) * CDIM + c0 + cc;
        T[lq + i * 4][cc] = (bf2f(in[idx]) - mean) * rstd + bf2f(res[idx]);
    }
    __syncthreads();
    int ll = tid & 63;
    int cr = tid >> 6;
    #pragma unroll
    for (int i = 0; i < 16; ++i) {
        int c = cr + i * 4;
        outf[((size_t)b * CDIM + c0 + c) * L + l0 + ll] = T[ll][c];
    }
}

// ---------------------------------------------------------------------------
// MFMA 32x32 windowed cross attention, 64-kpos chunked double-buffered KV
// pipeline. Fixed-max softmax (P = exp2(s - 24); scores statically bounded
// |s| << 24 for instance-normalized q,k) -> no fmax tree / ballot / rescale.
// V LDS col-XOR swizzle ((vc8&6)<<2 u16) -> write conflicts 4-way -> 1-way.
// 1D grid (704) XCD-grouped. K-norm folded into Q; V-norm in epilogue.
// ---------------------------------------------------------------------------
__global__ __launch_bounds__(512, 2)
void attn_win_mfma32(const ushort_t* __restrict__ qT, const ushort_t* __restrict__ kT,
                     const ushort_t* __restrict__ vT,
                     const float* __restrict__ vmean, const float* __restrict__ vrstd,
                     ushort_t* __restrict__ win)
{
    __shared__ __align__(16) char KB[2][8192];         // K chunk: [64 kpos][64 d], swizzled
    __shared__ __align__(16) ushort_t VBv[2][64][68];  // V^T chunk: [64 d][64 kpos], col-XOR
    __shared__ float VMS[64], VRS[64];

    int p = blockIdx.x;
    int xcd = p & 7;
    int sub = p >> 3;              // 0..87
    int g9 = xcd * 11 + (sub % 11);
    int hh = sub / 11;             // 0..7
    int n = g9 % 22, b = g9 / 22;

    int s = n * WSTRIDE;
    int es = 2 * s;
    bool tail = (n == NWIN - 1);
    int nch = tail ? 2 : 8;

    int tid = threadIdx.x;
    int lane = tid & 63;
    int w = tid >> 6;
    int l31 = lane & 31;
    int hf = lane >> 5;
    bool active = (!tail) || (w < 2);

    if (tid < 64) {
        int c = b * CDIM + hh * HD + tid;
        VMS[tid] = vmean[c];
        VRS[tid] = vrstd[c];
    }

    const ushort_t* kbase = kT + ((size_t)b * LEE + es) * CDIM + hh * HD;
    const ushort_t* vbase = vT + ((size_t)b * LEE + es) * CDIM + hh * HD;

    int vc8 = tid & 7;
    int vkp = tid >> 3;            // 0..63 (only <32 used for V)
    bool vdo = (tid < 256);
    int vcs = (vc8 & 6) << 2;      // col-XOR swizzle (u16 units, 16B granular)

    // K granule (1 per thread per chunk): 512 granules of 16B
    int kpos0 = tid >> 3;
    int kc8 = (tid & 7) ^ (kpos0 & 7);
    const ushort_t* ksrc = kbase + (size_t)kpos0 * CDIM + kc8 * 8;

    // chunk 0 staged up-front
    {
        gload16(ksrc, &KB[0][tid * 16]);
        if (vdo) {
            const ushort_t* src = vbase + (size_t)(2 * vkp) * CDIM + vc8 * 8;
            u16x8 wa = *reinterpret_cast<const u16x8*>(src);
            u16x8 wb = *reinterpret_cast<const u16x8*>(src + CDIM);
            #pragma unroll
            for (int j = 0; j < 8; ++j) {
                int d = vc8 * 8 + j;
                uint32_t dw = (uint32_t)wa[j] | ((uint32_t)wb[j] << 16);
                *reinterpret_cast<uint32_t*>(&VBv[0][d][(2 * vkp) ^ vcs]) = dw;
            }
        }
    }

    // Q fragments (B-operand: col q = lane&31, k elems d = kd*16 + hf*8 + j)
    bf16x8 bq[4];
    if (active) {
        int qrow_g = s + w * 32 + l31;
        const ushort_t* qp = qT + ((size_t)b * LDD + qrow_g) * CDIM + hh * HD;
        #pragma unroll
        for (int kd = 0; kd < 4; ++kd)
            bq[kd] = *reinterpret_cast<const bf16x8*>(qp + kd * 16 + hf * 8);
    }

    f32x16 acc0, acc1;
    #pragma unroll
    for (int e = 0; e < 16; ++e) { acc0[e] = 0.f; acc1[e] = 0.f; }
    float ssum = 0.f;
    int swk = (lane & 7) << 4;
    // read-side V col swizzle: d row knows its writer's vc8 = d>>3
    int vrs0 = ((l31 >> 3) & 6) << 2;          // for rows d = l31
    int vrs1 = (((l31 + 32) >> 3) & 6) << 2;   // for rows d = l31+32

    for (int ch = 0; ch < nch; ++ch) {
        int buf = ch & 1;
        __syncthreads();                       // chunk ch staged; buf^1 free

        u16x8 wa, wb;
        bool pf = (ch + 1 < nch);
        if (pf) {
            // K prefetch: async direct-to-LDS
            gload16(ksrc + (size_t)((ch + 1) * 64) * CDIM, &KB[buf ^ 1][tid * 16]);
            // V prefetch: issue loads now, write LDS after compute (T14)
            if (vdo) {
                const ushort_t* src = vbase + (size_t)((ch + 1) * 64 + 2 * vkp) * CDIM + vc8 * 8;
                wa = *reinterpret_cast<const u16x8*>(src);
                wb = *reinterpret_cast<const u16x8*>(src + CDIM);
            }
        }

        if (active) {
            // ---- S^T: A = K rows kpos, B = Q ----
            f32x16 st0, st1;
            #pragma unroll
            for (int e = 0; e < 16; ++e) { st0[e] = 0.f; st1[e] = 0.f; }
            const char* KA0 = &KB[buf][l31 * 128];
            const char* KA1 = KA0 + 32 * 128;
            __builtin_amdgcn_s_setprio(1);
            #pragma unroll
            for (int kd = 0; kd < 4; ++kd) {
                int co = (kd * 32 + hf * 16) ^ swk;
                bf16x8 ka0 = *reinterpret_cast<const bf16x8*>(KA0 + co);
                bf16x8 ka1 = *reinterpret_cast<const bf16x8*>(KA1 + co);
                st0 = __builtin_amdgcn_mfma_f32_32x32x16_bf16(ka0, bq[kd], st0, 0, 0, 0);
                st1 = __builtin_amdgcn_mfma_f32_32x32x16_bf16(ka1, bq[kd], st1, 0, 0, 0);
            }
            __builtin_amdgcn_s_setprio(0);
            // ---- fixed-max softmax: P = exp2(s - 24), linear-combinable ----
            uint32_t pk0[8], pk1[8];
            float ls = 0.f;
            #pragma unroll
            for (int pp = 0; pp < 8; ++pp) {
                float a = exp2f(st0[2 * pp] - 24.f), bb = exp2f(st0[2 * pp + 1] - 24.f);
                float c = exp2f(st1[2 * pp] - 24.f), dd = exp2f(st1[2 * pp + 1] - 24.f);
                ls += (a + bb) + (c + dd);
                pk0[pp] = pack2(a, bb);
                pk1[pp] = pack2(c, dd);
            }
            ssum += ls;
            // ---- PV: O^T += V^T . P^T ----
            __builtin_amdgcn_s_setprio(1);
            #pragma unroll
            for (int kc = 0; kc < 4; ++kc) {
                const int sub2 = kc & 1;
                uint32_t pA0, pA1, pA2, pA3;
                if ((kc >> 1) == 0) { pA0 = pk0[4*sub2]; pA1 = pk0[4*sub2+1]; pA2 = pk0[4*sub2+2]; pA3 = pk0[4*sub2+3]; }
                else                { pA0 = pk1[4*sub2]; pA1 = pk1[4*sub2+1]; pA2 = pk1[4*sub2+2]; pA3 = pk1[4*sub2+3]; }
                uint32_t s0 = hf ? pA0 : pA2;
                uint32_t s1 = hf ? pA1 : pA3;
                uint32_t r0 = (uint32_t)__shfl_xor((int)s0, 32);
                uint32_t r1 = (uint32_t)__shfl_xor((int)s1, 32);
                u32x4 bt;
                bt[0] = hf ? r0 : pA0;
                bt[1] = hf ? r1 : pA1;
                bt[2] = hf ? pA2 : r0;
                bt[3] = hf ? pA3 : r1;
                bf16x8 pbf = __builtin_bit_cast(bf16x8, bt);
                int ko = kc * 16 + hf * 8;
                const uint32_t* vr0p = reinterpret_cast<const uint32_t*>(&VBv[buf][l31][ko ^ vrs0]);
                const uint32_t* vr1p = reinterpret_cast<const uint32_t*>(&VBv[buf][l31 + 32][ko ^ vrs1]);
                u32x2 alo = *reinterpret_cast<const u32x2*>(vr0p);
                u32x2 ahi = *reinterpret_cast<const u32x2*>(vr0p + 2);
                u32x2 blo = *reinterpret_cast<const u32x2*>(vr1p);
                u32x2 bhi = *reinterpret_cast<const u32x2*>(vr1p + 2);
                u32x4 va0u, va1u;
                va0u[0] = alo[0]; va0u[1] = alo[1]; va0u[2] = ahi[0]; va0u[3] = ahi[1];
                va1u[0] = blo[0]; va1u[1] = blo[1]; va1u[2] = bhi[0]; va1u[3] = bhi[1];
                bf16x8 va0 = __builtin_bit_cast(bf16x8, va0u);
                bf16x8 va1 = __builtin_bit_cast(bf16x8, va1u);
                acc0 = __builtin_amdgcn_mfma_f32_32x32x16_bf16(va0, pbf, acc0, 0, 0, 0);
                acc1 = __builtin_amdgcn_mfma_f32_32x32x16_bf16(va1, pbf, acc1, 0, 0, 0);
            }
            __builtin_amdgcn_s_setprio(0);
        }

        if (pf && vdo) {
            // V write (loads have drained under compute)
            #pragma unroll
            for (int j = 0; j < 8; ++j) {
                int d = vc8 * 8 + j;
                uint32_t dw = (uint32_t)wa[j] | ((uint32_t)wb[j] << 16);
                *reinterpret_cast<uint32_t*>(&VBv[buf ^ 1][d][(2 * vkp) ^ vcs]) = dw;
            }
        }
    }

    // ---- epilogue: out = rV * (acc/sum - muV) ----
    if (active) {
        float stot = ssum + __shfl_xor(ssum, 32);
        float rs = 1.f / stot;
        size_t wbase = (((size_t)(b * NHEAD + hh) * NWIN + n) * WINQ + (size_t)(w * 32 + l31)) * HD;
        #pragma unroll
        for (int p4 = 0; p4 < 4; ++p4) {
            int d0 = p4 * 8 + hf * 4;
            float o0[4], o1[4];
            #pragma unroll
            for (int e = 0; e < 4; ++e) {
                o0[e] = VRS[d0 + e] * (acc0[4 * p4 + e] * rs - VMS[d0 + e]);
                o1[e] = VRS[32 + d0 + e] * (acc1[4 * p4 + e] * rs - VMS[32 + d0 + e]);
            }
            u32x2 w0, w1v;
            w0[0] = pack2(o0[0], o0[1]); w0[1] = pack2(o0[2], o0[3]);
            w1v[0] = pack2(o1[0], o1[1]); w1v[1] = pack2(o1[2], o1[3]);
            *reinterpret_cast<u32x2*>(&win[wbase + p4 * 8 + hf * 4]) = w0;
            *reinterpret_cast<u32x2*>(&win[wbase + 32 + p4 * 8 + hf * 4]) = w1v;
        }
    }
}

// ---------------------------------------------------------------------------
// Overlap-add + count-normalize (bf16 win) -> bf16 [B][L][CDIM].
// grid (LDD/64, NHEAD, NB)
// ---------------------------------------------------------------------------
__global__ __launch_bounds__(256)
void attn_finalize(const ushort_t* __restrict__ win, ushort_t* __restrict__ outT)
{
    int l0 = blockIdx.x * 64;
    int hh = blockIdx.y, b = blockIdx.z;
    int tid = threadIdx.x;
    int d2 = tid & 31;
    int lq = tid >> 5;
    #pragma unroll
    for (int i = 0; i < 8; ++i) {
        int ll = lq + i * 8;
        int l = l0 + ll;
        int n1 = min(NWIN - 1, l / WSTRIDE);
        int n0 = (l >= 64) ? ((l - 64) / WSTRIDE) : 0;
        float a0 = 0.f, a1 = 0.f;
        for (int nn = n0; nn <= n1; ++nn) {
            int qrow = l - nn * WSTRIDE;
            uint32_t v = *reinterpret_cast<const uint32_t*>(
                &win[(((size_t)(b * NHEAD + hh) * NWIN + nn) * WINQ + qrow) * HD + d2 * 2]);
            a0 += bf2f((ushort_t)(v & 0xffffu));
            a1 += bf2f((ushort_t)(v >> 16));
        }
        float inv = 1.f / (float)(n1 - n0 + 1);
        uint32_t o = pack2(a0 * inv, a1 * inv);
        *reinterpret_cast<uint32_t*>(
            &outT[((size_t)b * LDD + l) * CDIM + hh * HD + d2 * 2]) = o;
    }
}

// ---------------------------------------------------------------------------
extern "C" void kernel_launch(void* const* d_in, const int* in_sizes, int n_in,
                              void* d_out, int out_size, void* d_ws, size_t ws_size,
                              hipStream_t stream)
{
    const float* x_dec = (const float*)d_in[0];
    const float* x_enc = (const float*)d_in[1];
    const float* wq = (const float*)d_in[2];
    const float* bq = (const float*)d_in[3];
    const float* wk = (const float*)d_in[4];
    const float* bk = (const float*)d_in[5];
    const float* wv = (const float*)d_in[6];
    const float* bv = (const float*)d_in[7];
    const float* wo = (const float*)d_in[8];
    const float* bo = (const float*)d_in[9];
    const float* w1 = (const float*)d_in[10];
    const float* b1 = (const float*)d_in[11];
    const float* w2 = (const float*)d_in[12];
    const float* b2 = (const float*)d_in[13];
    float* out = (float*)d_out;

    // ---- workspace carve (bytes) ----
    char* base = (char*)d_ws;
    ushort_t* wqb = (ushort_t*)(base);
    ushort_t* wkb = (ushort_t*)(base + 524288);
    ushort_t* wvb = (ushort_t*)(base + 786432);
    ushort_t* wob = (ushort_t*)(base + 1048576);
    ushort_t* w1b = (ushort_t*)(base + 1572864);
    ushort_t* w2b = (ushort_t*)(base + 3670016);
    ushort_t* x_decT_b = (ushort_t*)(base + 5767168);    // 16.8 MB
    ushort_t* q_pre    = (ushort_t*)(base + 22544384);   // 16.8 MB -> xo_pre/xres
    ushort_t* k_pre    = (ushort_t*)(base + 39321600);   // 33.5 MB -> hT (with v)
    ushort_t* v_pre    = (ushort_t*)(base + 72876032);   // 33.5 MB
    ushort_t* x_encT_b = (ushort_t*)(base + 106430464);  // 16.8 MB -> attn_outT
    ushort_t* winb     = (ushort_t*)(base + 123207680);  // 23.1 MB bf16 -> y_pre
    float*    partQ    = (float*)(base + 169345024);     // 1 MB
    float*    partK    = (float*)(base + 170393600);     // 1 MB
    float*    partV    = (float*)(base + 171442176);     // 1 MB
    float*    km       = (float*)(base + 172490752);     // 8 KB each
    float*    krs      = km + 2048;
    float*    vm       = krs + 2048;
    float*    vrs      = vm + 2048;
    ushort_t* attn_outT = x_encT_b;
    ushort_t* xo_pre   = q_pre;
    ushort_t* hT       = k_pre;
    ushort_t* y_pre    = winb;

    dim3 blk(256);
    dim3 blk512(512);

    // 0. weights -> bf16
    Cvt6Args ca;
    ca.src[0] = wq; ca.src[1] = wk; ca.src[2] = wv;
    ca.src[3] = wo; ca.src[4] = w1; ca.src[5] = w2;
    ca.dst[0] = wqb; ca.dst[1] = wkb; ca.dst[2] = wvb;
    ca.dst[3] = wob; ca.dst[4] = w1b; ca.dst[5] = w2b;
    ca.n[0] = 262144; ca.n[1] = 131072; ca.n[2] = 131072;
    ca.n[3] = 262144; ca.n[4] = 1048576; ca.n[5] = 1048576;
    cvt6<<<dim3(1024, 6), blk, 0, stream>>>(ca);

    // 1. transpose inputs to [B][L][C] bf16
    tcvt<<<dim3(LDD / 64, CDIM / 64, NB), blk, 0, stream>>>(x_dec, x_decT_b, CDIM, LDD);
    tcvt<<<dim3(LEE / 64, CENC / 64, NB), blk, 0, stream>>>(x_enc, x_encT_b, CENC, LEE);

    const float QSCALE = 0.125f * 1.4426950408889634f;   // 1/sqrt(hd) * log2(e)

    // 2-4. q/k/v GEMMs (k/v stay RAW; stats captured for fused norms)
    mgemm256<0,1><<<dim3(CDIM / 256, LDD / 256, NB), blk512, 0, stream>>>(x_decT_b, wqb, bq, q_pre, partQ, LDD, CDIM, CDIM);
    mgemm256<0,1><<<dim3(CDIM / 256, LEE / 256, NB), blk512, 0, stream>>>(x_encT_b, wkb, bk, k_pre, partK, LEE, CDIM, CENC);
    mgemm256<0,1><<<dim3(CDIM / 256, LEE / 256, NB), blk512, 0, stream>>>(x_encT_b, wvb, bv, v_pre, partV, LEE, CDIM, CENC);
    stats_finish<<<dim3(8), blk, 0, stream>>>(partK, partV, km, krs, vm, vrs, LEE / 256);

    // 5. q normalized, folded with K's rstd
    cn_apply_v<0><<<dim3(LDD / 16, 1, NB), blk, 0, stream>>>(q_pre, partQ, nullptr, q_pre, krs, LDD, LDD / 256, QSCALE);

    // 6. windowed attention (64-kpos chunked pipeline) + overlap-add
    attn_win_mfma32<<<dim3(NWIN * NHEAD * NB), blk512, 0, stream>>>(q_pre, k_pre, v_pre, vm, vrs, winb);
    attn_finalize<<<dim3(LDD / 64, NHEAD, NB), blk, 0, stream>>>(winb, attn_outT);

    // 7. xres = IN(attn_outT @ wo^T + bo) + x_decT
    mgemm256<0,1><<<dim3(CDIM / 256, LDD / 256, NB), blk512, 0, stream>>>(attn_outT, wob, bo, xo_pre, partQ, LDD, CDIM, CDIM);
    cn_apply_v<1><<<dim3(LDD / 16, 1, NB), blk, 0, stream>>>(xo_pre, partQ, x_decT_b, xo_pre, nullptr, LDD, LDD / 256, 1.0f);

    // 8. h = gelu(xres @ w1^T + b1)
    mgemm256<1,0><<<dim3(HDIM / 256, LDD / 256, NB), blk512, 0, stream>>>(xo_pre, w1b, b1, hT, nullptr, LDD, HDIM, CDIM);

    // 9. y = IN(h @ w2^T + b2) + xres -> f32 [B][C][L]
    mgemm256<0,1><<<dim3(CDIM / 256, LDD / 256, NB), blk512, 0, stream>>>(hT, w2b, b2, y_pre, partQ, LDD, CDIM, HDIM);
    cn_apply_t<<<dim3(CDIM / 64, LDD / 64, NB), blk, 0, stream>>>(y_pre, partQ, xo_pre, out, LDD, LDD / 256);

    (void)in_sizes; (void)n_in; (void)out_size; (void)ws_size;
}

// Round 10
// 331.771 us; speedup vs baseline: 1.1303x; 1.1303x over previous
//
#include <hip/hip_runtime.h>
#include <hip/hip_bf16.h>
#include <math.h>
#include <stdint.h>

#define LDD 4096
#define LEE 8192
#define CDIM 512
#define CENC 256
#define HDIM 2048
#define NB 4
#define NHEAD 8
#define HD 64
#define NWIN 22
#define WINQ 256
#define WSTRIDE 192
#define KVS 1024   // row stride of fused k|v tensor

typedef __attribute__((ext_vector_type(8))) short bf16x8;
typedef __attribute__((ext_vector_type(8))) unsigned short u16x8;
typedef __attribute__((ext_vector_type(4))) float f32x4;
typedef __attribute__((ext_vector_type(16))) float f32x16;
typedef __attribute__((ext_vector_type(2))) unsigned int u32x2;
typedef __attribute__((ext_vector_type(4))) unsigned int u32x4;
typedef unsigned short ushort_t;

__device__ __forceinline__ uint32_t pack2(float lo, float hi) {
    return ((__float_as_uint(hi) + 0x8000u) & 0xffff0000u) |
           ((__float_as_uint(lo) + 0x8000u) >> 16);
}
__device__ __forceinline__ ushort_t bfc(float x) {
    return (ushort_t)((__float_as_uint(x) + 0x8000u) >> 16);
}
__device__ __forceinline__ float bf2f(ushort_t u) {
    return __uint_as_float(((uint32_t)u) << 16);
}
__device__ __forceinline__ void gload16(const void* g, void* l) {
    __builtin_amdgcn_global_load_lds(
        (const __attribute__((address_space(1))) void*)g,
        (__attribute__((address_space(3))) void*)l, 16, 0, 0);
}
// fast erf-based gelu (A&S 7.1.26, |eps| <= 1.5e-7)
__device__ __forceinline__ float gelu_fast(float x) {
    float z = fabsf(x) * 0.70710678f;
    float t = 1.0f / fmaf(0.3275911f, z, 1.0f);
    float p = t * fmaf(t, fmaf(t, fmaf(t, fmaf(t, 1.061405429f, -1.453152027f),
                                        1.421413741f), -0.284496736f), 0.254829592f);
    float e = __expf(-z * z);
    float erfz = fmaf(-p, e, 1.0f);
    float sgn = copysignf(erfz, x);
    return 0.5f * x * (1.0f + sgn);
}

// ---------------------------------------------------------------------------
// Weights f32 -> bf16, 6 segments in one launch. grid (1024, 6).
// wk and wv land adjacent -> usable as one stacked [1024][256] matrix.
// ---------------------------------------------------------------------------
struct Cvt6Args {
    const float* src[6];
    ushort_t* dst[6];
    int n[6];
};
__global__ __launch_bounds__(256)
void cvt6(Cvt6Args a)
{
    int seg = blockIdx.y;
    int i = (blockIdx.x * 256 + threadIdx.x) * 4;
    if (i < a.n[seg]) {
        float4 v = *reinterpret_cast<const float4*>(&a.src[seg][i]);
        u32x2 p; p[0] = pack2(v.x, v.y); p[1] = pack2(v.z, v.w);
        *reinterpret_cast<u32x2*>(&a.dst[seg][i]) = p;
    }
}

// stack bk||bv into f32[1024]. grid(4)x256.
__global__ __launch_bounds__(256)
void bias_stack(const float* __restrict__ bk, const float* __restrict__ bv,
                float* __restrict__ bkv)
{
    int t = blockIdx.x * 256 + threadIdx.x;
    bkv[t] = (t < 512) ? bk[t] : bv[t - 512];
}

// ---------------------------------------------------------------------------
// Transpose+convert: f32 [B][C][L] -> bf16 [B][L][C]. grid (L/64, C/64, B)
// ---------------------------------------------------------------------------
__global__ __launch_bounds__(256)
void tcvt(const float* __restrict__ in, ushort_t* __restrict__ outb, int C, int L)
{
    __shared__ float T[64][65];
    int l0 = blockIdx.x * 64, c0 = blockIdx.y * 64, b = blockIdx.z;
    int tid = threadIdx.x;
    int ll = tid & 63, cq = tid >> 6;
    #pragma unroll
    for (int i = 0; i < 16; ++i) {
        int c = cq + i * 4;
        T[c][ll] = in[((size_t)b * C + c0 + c) * L + l0 + ll];
    }
    __syncthreads();
    int cc = tid & 63, lq = tid >> 6;
    #pragma unroll
    for (int i = 0; i < 16; ++i) {
        int l = lq + i * 4;
        outb[((size_t)b * L + l0 + l) * C + c0 + cc] = bfc(T[cc][l]);
    }
}

// ---------------------------------------------------------------------------
// MFMA GEMM (2-phase prefetch, BK=64): Out[b][m][n] = ep(sum_k A[m][k]W[n][k]+bias[n])
// PROVEN structure: 128x128 tile, 4 waves, 2-buffer LDS, 2 blocks/CU.
// ---------------------------------------------------------------------------
template<int EPI, int STATS>
__global__ __launch_bounds__(256)
void mgemm2(const ushort_t* __restrict__ A, const ushort_t* __restrict__ Wt,
            const float* __restrict__ bias, ushort_t* __restrict__ Out,
            float* __restrict__ part, int M, int N, int K)
{
    __shared__ __align__(16) ushort_t As[2][8192];
    __shared__ __align__(16) ushort_t Bs[2][8192];

    int Nt = gridDim.x;
    int flat = blockIdx.y * Nt + blockIdx.x;
    int nwg = Nt * gridDim.y;
    int swz = (flat & 7) * (nwg >> 3) + (flat >> 3);   // nwg % 8 == 0 all shapes
    int nb = swz % Nt, mb = swz / Nt;
    int b = blockIdx.z;
    int m0 = mb * 128, n0 = nb * 128;

    int tid = threadIdx.x;
    int lane = tid & 63;
    int w = tid >> 6;
    int q16 = lane & 15, g = lane >> 4;
    int wr = w >> 1, wc = w & 1;

    const ushort_t* Ag[4]; const ushort_t* Wg[4];
    #pragma unroll
    for (int i = 0; i < 4; ++i) {
        int gran = w * 256 + i * 64 + lane;
        int row = gran >> 3;
        int c8 = (gran & 7) ^ (row & 7);
        Ag[i] = A + ((size_t)b * M + m0 + row) * K + c8 * 8;
        Wg[i] = Wt + ((size_t)(n0 + row)) * K + c8 * 8;
    }

    f32x4 acc[4][4];
    #pragma unroll
    for (int mt = 0; mt < 4; ++mt)
        #pragma unroll
        for (int nt = 0; nt < 4; ++nt) {
            acc[mt][nt][0] = 0.f; acc[mt][nt][1] = 0.f;
            acc[mt][nt][2] = 0.f; acc[mt][nt][3] = 0.f;
        }

    #pragma unroll
    for (int i = 0; i < 4; ++i) {
        gload16(Ag[i], &As[0][w * 2048 + i * 512]);
        gload16(Wg[i], &Bs[0][w * 2048 + i * 512]);
    }

    int NTILES = K >> 6;
    for (int kt = 0; kt < NTILES; ++kt) {
        int cur = kt & 1;
        __syncthreads();
        if (kt + 1 < NTILES) {
            int k0 = (kt + 1) << 6;
            #pragma unroll
            for (int i = 0; i < 4; ++i) {
                gload16(Ag[i] + k0, &As[cur ^ 1][w * 2048 + i * 512]);
                gload16(Wg[i] + k0, &Bs[cur ^ 1][w * 2048 + i * 512]);
            }
        }
        const char* Ab = (const char*)&As[cur][0];
        const char* Bb = (const char*)&Bs[cur][0];
        bf16x8 ka[4][2], kb[4][2];
        #pragma unroll
        for (int mt = 0; mt < 4; ++mt) {
            int r = wr * 64 + mt * 16 + q16;
            int rb = r * 128;
            int sw8 = (r & 7) << 4;
            ka[mt][0] = *reinterpret_cast<const bf16x8*>(Ab + rb + ((g * 16) ^ sw8));
            ka[mt][1] = *reinterpret_cast<const bf16x8*>(Ab + rb + ((64 + g * 16) ^ sw8));
        }
        #pragma unroll
        for (int nt = 0; nt < 4; ++nt) {
            int r = wc * 64 + nt * 16 + q16;
            int rb = r * 128;
            int sw8 = (r & 7) << 4;
            kb[nt][0] = *reinterpret_cast<const bf16x8*>(Bb + rb + ((g * 16) ^ sw8));
            kb[nt][1] = *reinterpret_cast<const bf16x8*>(Bb + rb + ((64 + g * 16) ^ sw8));
        }
        #pragma unroll
        for (int mt = 0; mt < 4; ++mt)
            #pragma unroll
            for (int nt = 0; nt < 4; ++nt) {
                acc[mt][nt] = __builtin_amdgcn_mfma_f32_16x16x32_bf16(kb[nt][0], ka[mt][0], acc[mt][nt], 0, 0, 0);
                acc[mt][nt] = __builtin_amdgcn_mfma_f32_16x16x32_bf16(kb[nt][1], ka[mt][1], acc[mt][nt], 0, 0, 0);
            }
    }

    float4 bv4[4];
    #pragma unroll
    for (int nt = 0; nt < 4; ++nt)
        bv4[nt] = *reinterpret_cast<const float4*>(&bias[n0 + wc * 64 + nt * 16 + g * 4]);

    float s_[4][4], q_[4][4];
    if (STATS) {
        #pragma unroll
        for (int nt = 0; nt < 4; ++nt)
            #pragma unroll
            for (int r = 0; r < 4; ++r) { s_[nt][r] = 0.f; q_[nt][r] = 0.f; }
    }

    #pragma unroll
    for (int mt = 0; mt < 4; ++mt) {
        int m = m0 + wr * 64 + mt * 16 + q16;
        size_t rowoff = ((size_t)b * M + m) * N;
        #pragma unroll
        for (int nt = 0; nt < 4; ++nt) {
            float vv[4];
            #pragma unroll
            for (int r = 0; r < 4; ++r) {
                float val = acc[mt][nt][r] + ((const float*)&bv4[nt])[r];
                if (EPI == 1) val = gelu_fast(val);
                if (STATS) { s_[nt][r] += val; q_[nt][r] = fmaf(val, val, q_[nt][r]); }
                vv[r] = val;
            }
            u32x2 pk; pk[0] = pack2(vv[0], vv[1]); pk[1] = pack2(vv[2], vv[3]);
            *reinterpret_cast<u32x2*>(&Out[rowoff + n0 + wc * 64 + nt * 16 + g * 4]) = pk;
        }
    }

    if (STATS) {
        __syncthreads();
        float* SS = (float*)&As[0][0];   // [128][33]
        float* SQ = (float*)&Bs[0][0];
        #pragma unroll
        for (int nt = 0; nt < 4; ++nt)
            #pragma unroll
            for (int r = 0; r < 4; ++r) {
                int nl = wc * 64 + nt * 16 + g * 4 + r;
                SS[nl * 33 + wr * 16 + q16] = s_[nt][r];
                SQ[nl * 33 + wr * 16 + q16] = q_[nt][r];
            }
        __syncthreads();
        if (tid < 128) {
            float ts = 0.f, tq = 0.f;
            #pragma unroll 8
            for (int j = 0; j < 32; ++j) { ts += SS[tid * 33 + j]; tq += SQ[tid * 33 + j]; }
            size_t po = (((size_t)b * (M >> 7) + mb) * N + n0 + tid) * 2;
            part[po] = ts; part[po + 1] = tq;
        }
    }
}

// ---------------------------------------------------------------------------
// Finish stats: partQ [b][32][512][2] (q, over LDD) and partKV [b][64][1024][2]
// (k cols 0-511, v cols 512-1023, over LEE) -> qm, qr(=rq*rk*QSCALE), vm, vr.
// grid (8) x 256: one thread per (b, c).
// ---------------------------------------------------------------------------
__global__ __launch_bounds__(256)
void stats_finish(const float* __restrict__ pq, const float* __restrict__ pkv,
                  float* __restrict__ qm, float* __restrict__ qr,
                  float* __restrict__ vm, float* __restrict__ vr, float qscale)
{
    int id = blockIdx.x * 256 + threadIdx.x;   // 0..2047
    int b = id >> 9, c = id & 511;
    float sq = 0.f, qq = 0.f;
    for (int sp = 0; sp < 32; ++sp) {
        size_t po = (((size_t)(b * 32 + sp)) * CDIM + c) * 2;
        sq += pq[po]; qq += pq[po + 1];
    }
    float sk = 0.f, qk = 0.f, sv = 0.f, qv = 0.f;
    for (int sp = 0; sp < 64; ++sp) {
        size_t po = (((size_t)(b * 64 + sp)) * KVS + c) * 2;
        sk += pkv[po]; qk += pkv[po + 1];
        sv += pkv[po + 1024]; qv += pkv[po + 1025];
    }
    float mq = sq / (float)LDD;
    float rq = rsqrtf(qq / (float)LDD - mq * mq + 1e-5f);
    float mk = sk / (float)LEE;
    float rk = rsqrtf(qk / (float)LEE - mk * mk + 1e-5f);
    float mv = sv / (float)LEE;
    qm[id] = mq;
    qr[id] = rq * rk * qscale;
    vm[id] = mv;
    vr[id] = rsqrtf(qv / (float)LEE - mv * mv + 1e-5f);
}

// ---------------------------------------------------------------------------
// Column-norm apply (vectorized, bf16 in/out, C=512). grid (L/16, 1, B).
// ---------------------------------------------------------------------------
template<int RES>
__global__ __launch_bounds__(256)
void cn_apply_v(const ushort_t* __restrict__ in, const float* __restrict__ part,
                const ushort_t* __restrict__ res, ushort_t* __restrict__ out,
                int L, int SPLITM)
{
    __shared__ float SM[CDIM], SR[CDIM];
    int b = blockIdx.z;
    int tid = threadIdx.x;
    for (int c = tid; c < CDIM; c += 256) {
        float fs = 0.f, fq = 0.f;
        for (int sp = 0; sp < SPLITM; ++sp) {
            size_t po = (((size_t)b * SPLITM + sp) * CDIM + c) * 2;
            fs += part[po]; fq += part[po + 1];
        }
        float mean = fs / (float)L;
        float var = fq / (float)L - mean * mean;
        SM[c] = mean; SR[c] = rsqrtf(var + 1e-5f);
    }
    __syncthreads();
    int c0 = (tid & 63) * 8;
    int l0 = blockIdx.x * 16 + (tid >> 6) * 4;
    float mm[8], rr[8];
    #pragma unroll
    for (int j = 0; j < 8; ++j) { mm[j] = SM[c0 + j]; rr[j] = SR[c0 + j]; }
    #pragma unroll
    for (int i = 0; i < 4; ++i) {
        int l = l0 + i;
        size_t off = ((size_t)b * L + l) * CDIM + c0;
        u16x8 v = *reinterpret_cast<const u16x8*>(in + off);
        u16x8 rv;
        if (RES) rv = *reinterpret_cast<const u16x8*>(res + off);
        u16x8 o;
        #pragma unroll
        for (int j = 0; j < 8; ++j) {
            float y = (bf2f((ushort_t)v[j]) - mm[j]) * rr[j];
            if (RES) y += bf2f((ushort_t)rv[j]);
            o[j] = bfc(y);
        }
        *reinterpret_cast<u16x8*>(out + off) = o;
    }
}

// ---------------------------------------------------------------------------
// Final: out[B][C][L] f32 = norm(in)[l][c] + res[l][c], transposed write.
// ---------------------------------------------------------------------------
__global__ __launch_bounds__(256)
void cn_apply_t(const ushort_t* __restrict__ in, const float* __restrict__ part,
                const ushort_t* __restrict__ res, float* __restrict__ outf,
                int L, int SPLITM)
{
    __shared__ float SM[64], SR[64];
    __shared__ float T[64][65];
    int b = blockIdx.z;
    int c0 = blockIdx.x * 64;
    int l0 = blockIdx.y * 64;
    int tid = threadIdx.x;
    if (tid < 64) {
        int c = c0 + tid;
        float fs = 0.f, fq = 0.f;
        for (int sp = 0; sp < SPLITM; ++sp) {
            size_t po = (((size_t)b * SPLITM + sp) * CDIM + c) * 2;
            fs += part[po]; fq += part[po + 1];
        }
        float mean = fs / (float)L;
        float var = fq / (float)L - mean * mean;
        SM[tid] = mean; SR[tid] = rsqrtf(var + 1e-5f);
    }
    __syncthreads();
    int cc = tid & 63;
    int lq = tid >> 6;
    float mean = SM[cc], rstd = SR[cc];
    #pragma unroll
    for (int i = 0; i < 16; ++i) {
        int l = l0 + lq + i * 4;
        size_t idx = ((size_t)b * L + l) * CDIM + c0 + cc;
        T[lq + i * 4][cc] = (bf2f(in[idx]) - mean) * rstd + bf2f(res[idx]);
    }
    __syncthreads();
    int ll = tid & 63;
    int cr = tid >> 6;
    #pragma unroll
    for (int i = 0; i < 16; ++i) {
        int c = cr + i * 4;
        outf[((size_t)b * CDIM + c0 + c) * L + l0 + ll] = T[ll][c];
    }
}

// ---------------------------------------------------------------------------
// MFMA 32x32 windowed cross attention, depth-2 K prefetch (3-buffer,
// counted vmcnt + raw barriers), V reg-staged depth-1 (compiler-tracked).
// ~43 KB LDS -> 3 blocks/CU -> all 704 blocks co-resident.
// q raw bf16 [B][L][512]; per-channel q-norm (qm, qr=rq*rk*QSCALE) applied at
// Q-fragment load. kv fused raw bf16 [B][L][1024] (k cols 0-511, v 512-1023).
// Fixed-max exp2(s-24) softmax; V-norm in epilogue. 1D grid (704) XCD-grouped.
// ---------------------------------------------------------------------------
__global__ __launch_bounds__(512, 2)
void attn_win_mfma32(const ushort_t* __restrict__ qT, const ushort_t* __restrict__ kvT,
                     const float* __restrict__ qmean, const float* __restrict__ qrs,
                     const float* __restrict__ vmean, const float* __restrict__ vrstd,
                     ushort_t* __restrict__ win)
{
    __shared__ __align__(16) char KB[3][8192];         // K chunk: [64 kpos][64 d], swizzled
    __shared__ __align__(16) ushort_t VBv[2][64][68];  // V^T chunk: [64 d][64 kpos], col-XOR
    __shared__ float VMS[64], VRS[64], QMS[64], QRS[64];

    int p = blockIdx.x;
    int xcd = p & 7;
    int sub = p >> 3;
    int g9 = xcd * 11 + (sub % 11);
    int hh = sub / 11;
    int n = g9 % 22, b = g9 / 22;

    int s = n * WSTRIDE;
    int es = 2 * s;
    bool tail = (n == NWIN - 1);
    int nch = tail ? 2 : 8;

    int tid = threadIdx.x;
    int lane = tid & 63;
    int w = tid >> 6;
    int l31 = lane & 31;
    int hf = lane >> 5;
    bool active = (!tail) || (w < 2);

    const ushort_t* kbase = kvT + ((size_t)b * LEE + es) * KVS + hh * HD;
    const ushort_t* vbase = kbase + 512;

    int vc8 = tid & 7;
    int vkp = tid >> 3;
    bool vdo = (tid < 256);
    int vcs = (vc8 & 6) << 2;

    int kpos0 = tid >> 3;
    int kc8 = (tid & 7) ^ (kpos0 & 7);
    const ushort_t* ksrc = kbase + (size_t)kpos0 * KVS + kc8 * 8;

    // ---- prologue: q raw loads (oldest), K0, V0 regs, K1, stats, V0 write ----
    u16x8 qraw[4];
    if (active) {
        int qrow_g = s + w * 32 + l31;
        const ushort_t* qp = qT + ((size_t)b * LDD + qrow_g) * CDIM + hh * HD;
        #pragma unroll
        for (int kd = 0; kd < 4; ++kd)
            qraw[kd] = *reinterpret_cast<const u16x8*>(qp + kd * 16 + hf * 8);
    }
    gload16(ksrc, &KB[0][tid * 16]);
    u16x8 wa0, wb0;
    if (vdo) {
        const ushort_t* src = vbase + (size_t)(2 * vkp) * KVS + vc8 * 8;
        wa0 = *reinterpret_cast<const u16x8*>(src);
        wb0 = *reinterpret_cast<const u16x8*>(src + KVS);
    }
    gload16(ksrc + (size_t)64 * KVS, &KB[1][tid * 16]);
    if (tid < 64) {
        int c = b * CDIM + hh * HD + tid;
        VMS[tid] = vmean[c]; VRS[tid] = vrstd[c];
        QMS[tid] = qmean[c]; QRS[tid] = qrs[c];
    }
    if (vdo) {
        #pragma unroll
        for (int j = 0; j < 8; ++j) {
            int d = vc8 * 8 + j;
            uint32_t dw = (uint32_t)wa0[j] | ((uint32_t)wb0[j] << 16);
            *reinterpret_cast<uint32_t*>(&VBv[0][d][(2 * vkp) ^ vcs]) = dw;
        }
    }
    asm volatile("s_waitcnt lgkmcnt(0)" ::: "memory");
    __builtin_amdgcn_s_barrier();

    // ---- build normalized Q fragments (stats now visible) ----
    bf16x8 bq[4];
    if (active) {
        #pragma unroll
        for (int kd = 0; kd < 4; ++kd) {
            u32x4 pk;
            #pragma unroll
            for (int jj = 0; jj < 4; ++jj) {
                int c0 = kd * 16 + hf * 8 + 2 * jj;
                float y0 = (bf2f((ushort_t)qraw[kd][2 * jj]) - QMS[c0]) * QRS[c0];
                float y1 = (bf2f((ushort_t)qraw[kd][2 * jj + 1]) - QMS[c0 + 1]) * QRS[c0 + 1];
                pk[jj] = pack2(y0, y1);
            }
            bq[kd] = __builtin_bit_cast(bf16x8, pk);
        }
    }

    f32x16 acc0, acc1;
    #pragma unroll
    for (int e = 0; e < 16; ++e) { acc0[e] = 0.f; acc1[e] = 0.f; }
    float ssum = 0.f;
    int swk = (lane & 7) << 4;
    int vrs0 = ((l31 >> 3) & 6) << 2;
    int vrs1 = (((l31 + 32) >> 3) & 6) << 2;

    for (int ch = 0; ch < nch; ++ch) {
        // K[ch] landed (own granule oldest; K[ch+1] may fly); prev ds writes retired
        asm volatile("s_waitcnt vmcnt(1) lgkmcnt(0)" ::: "memory");
        __builtin_amdgcn_s_barrier();

        u16x8 wa, wb;
        bool pfv = (ch + 1 < nch);
        if (pfv && vdo) {
            const ushort_t* src = vbase + (size_t)((ch + 1) * 64 + 2 * vkp) * KVS + vc8 * 8;
            wa = *reinterpret_cast<const u16x8*>(src);
            wb = *reinterpret_cast<const u16x8*>(src + KVS);
        }
        if (ch + 2 < nch)
            gload16(ksrc + (size_t)((ch + 2) * 64) * KVS, &KB[(ch + 2) % 3][tid * 16]);

        if (active) {
            // ---- S^T: A = K rows kpos, B = Q ----
            f32x16 st0, st1;
            #pragma unroll
            for (int e = 0; e < 16; ++e) { st0[e] = 0.f; st1[e] = 0.f; }
            const char* KA0 = &KB[ch % 3][l31 * 128];
            const char* KA1 = KA0 + 32 * 128;
            __builtin_amdgcn_s_setprio(1);
            #pragma unroll
            for (int kd = 0; kd < 4; ++kd) {
                int co = (kd * 32 + hf * 16) ^ swk;
                bf16x8 ka0 = *reinterpret_cast<const bf16x8*>(KA0 + co);
                bf16x8 ka1 = *reinterpret_cast<const bf16x8*>(KA1 + co);
                st0 = __builtin_amdgcn_mfma_f32_32x32x16_bf16(ka0, bq[kd], st0, 0, 0, 0);
                st1 = __builtin_amdgcn_mfma_f32_32x32x16_bf16(ka1, bq[kd], st1, 0, 0, 0);
            }
            __builtin_amdgcn_s_setprio(0);
            // ---- fixed-max softmax: P = exp2(s - 24) ----
            uint32_t pk0[8], pk1[8];
            float ls = 0.f;
            #pragma unroll
            for (int pp = 0; pp < 8; ++pp) {
                float a = exp2f(st0[2 * pp] - 24.f), bb = exp2f(st0[2 * pp + 1] - 24.f);
                float c = exp2f(st1[2 * pp] - 24.f), dd = exp2f(st1[2 * pp + 1] - 24.f);
                ls += (a + bb) + (c + dd);
                pk0[pp] = pack2(a, bb);
                pk1[pp] = pack2(c, dd);
            }
            ssum += ls;
            // ---- PV: O^T += V^T . P^T ----
            __builtin_amdgcn_s_setprio(1);
            #pragma unroll
            for (int kc = 0; kc < 4; ++kc) {
                const int sub2 = kc & 1;
                uint32_t pA0, pA1, pA2, pA3;
                if ((kc >> 1) == 0) { pA0 = pk0[4*sub2]; pA1 = pk0[4*sub2+1]; pA2 = pk0[4*sub2+2]; pA3 = pk0[4*sub2+3]; }
                else                { pA0 = pk1[4*sub2]; pA1 = pk1[4*sub2+1]; pA2 = pk1[4*sub2+2]; pA3 = pk1[4*sub2+3]; }
                uint32_t s0 = hf ? pA0 : pA2;
                uint32_t s1 = hf ? pA1 : pA3;
                uint32_t r0 = (uint32_t)__shfl_xor((int)s0, 32);
                uint32_t r1 = (uint32_t)__shfl_xor((int)s1, 32);
                u32x4 bt;
                bt[0] = hf ? r0 : pA0;
                bt[1] = hf ? r1 : pA1;
                bt[2] = hf ? pA2 : r0;
                bt[3] = hf ? pA3 : r1;
                bf16x8 pbf = __builtin_bit_cast(bf16x8, bt);
                int ko = kc * 16 + hf * 8;
                const uint32_t* vr0p = reinterpret_cast<const uint32_t*>(&VBv[ch & 1][l31][ko ^ vrs0]);
                const uint32_t* vr1p = reinterpret_cast<const uint32_t*>(&VBv[ch & 1][l31 + 32][ko ^ vrs1]);
                u32x2 alo = *reinterpret_cast<const u32x2*>(vr0p);
                u32x2 ahi = *reinterpret_cast<const u32x2*>(vr0p + 2);
                u32x2 blo = *reinterpret_cast<const u32x2*>(vr1p);
                u32x2 bhi = *reinterpret_cast<const u32x2*>(vr1p + 2);
                u32x4 va0u, va1u;
                va0u[0] = alo[0]; va0u[1] = alo[1]; va0u[2] = ahi[0]; va0u[3] = ahi[1];
                va1u[0] = blo[0]; va1u[1] = blo[1]; va1u[2] = bhi[0]; va1u[3] = bhi[1];
                bf16x8 va0 = __builtin_bit_cast(bf16x8, va0u);
                bf16x8 va1 = __builtin_bit_cast(bf16x8, va1u);
                acc0 = __builtin_amdgcn_mfma_f32_32x32x16_bf16(va0, pbf, acc0, 0, 0, 0);
                acc1 = __builtin_amdgcn_mfma_f32_32x32x16_bf16(va1, pbf, acc1, 0, 0, 0);
            }
            __builtin_amdgcn_s_setprio(0);
        }

        if (pfv && vdo) {
            #pragma unroll
            for (int j = 0; j < 8; ++j) {
                int d = vc8 * 8 + j;
                uint32_t dw = (uint32_t)wa[j] | ((uint32_t)wb[j] << 16);
                *reinterpret_cast<uint32_t*>(&VBv[(ch + 1) & 1][d][(2 * vkp) ^ vcs]) = dw;
            }
        }
    }

    // ---- epilogue: out = rV * (acc/sum - muV) ----
    if (active) {
        float stot = ssum + __shfl_xor(ssum, 32);
        float rs = 1.f / stot;
        size_t wbase = (((size_t)(b * NHEAD + hh) * NWIN + n) * WINQ + (size_t)(w * 32 + l31)) * HD;
        #pragma unroll
        for (int p4 = 0; p4 < 4; ++p4) {
            int d0 = p4 * 8 + hf * 4;
            float o0[4], o1[4];
            #pragma unroll
            for (int e = 0; e < 4; ++e) {
                o0[e] = VRS[d0 + e] * (acc0[4 * p4 + e] * rs - VMS[d0 + e]);
                o1[e] = VRS[32 + d0 + e] * (acc1[4 * p4 + e] * rs - VMS[32 + d0 + e]);
            }
            u32x2 w0, w1v;
            w0[0] = pack2(o0[0], o0[1]); w0[1] = pack2(o0[2], o0[3]);
            w1v[0] = pack2(o1[0], o1[1]); w1v[1] = pack2(o1[2], o1[3]);
            *reinterpret_cast<u32x2*>(&win[wbase + p4 * 8 + hf * 4]) = w0;
            *reinterpret_cast<u32x2*>(&win[wbase + 32 + p4 * 8 + hf * 4]) = w1v;
        }
    }
}

// ---------------------------------------------------------------------------
// Overlap-add + count-normalize (bf16 win) -> bf16 [B][L][CDIM].
// grid (LDD/64, NHEAD, NB)
// ---------------------------------------------------------------------------
__global__ __launch_bounds__(256)
void attn_finalize(const ushort_t* __restrict__ win, ushort_t* __restrict__ outT)
{
    int l0 = blockIdx.x * 64;
    int hh = blockIdx.y, b = blockIdx.z;
    int tid = threadIdx.x;
    int d2 = tid & 31;
    int lq = tid >> 5;
    #pragma unroll
    for (int i = 0; i < 8; ++i) {
        int ll = lq + i * 8;
        int l = l0 + ll;
        int n1 = min(NWIN - 1, l / WSTRIDE);
        int n0 = (l >= 64) ? ((l - 64) / WSTRIDE) : 0;
        float a0 = 0.f, a1 = 0.f;
        for (int nn = n0; nn <= n1; ++nn) {
            int qrow = l - nn * WSTRIDE;
            uint32_t v = *reinterpret_cast<const uint32_t*>(
                &win[(((size_t)(b * NHEAD + hh) * NWIN + nn) * WINQ + qrow) * HD + d2 * 2]);
            a0 += bf2f((ushort_t)(v & 0xffffu));
            a1 += bf2f((ushort_t)(v >> 16));
        }
        float inv = 1.f / (float)(n1 - n0 + 1);
        uint32_t o = pack2(a0 * inv, a1 * inv);
        *reinterpret_cast<uint32_t*>(
            &outT[((size_t)b * LDD + l) * CDIM + hh * HD + d2 * 2]) = o;
    }
}

// ---------------------------------------------------------------------------
extern "C" void kernel_launch(void* const* d_in, const int* in_sizes, int n_in,
                              void* d_out, int out_size, void* d_ws, size_t ws_size,
                              hipStream_t stream)
{
    const float* x_dec = (const float*)d_in[0];
    const float* x_enc = (const float*)d_in[1];
    const float* wq = (const float*)d_in[2];
    const float* bq = (const float*)d_in[3];
    const float* wk = (const float*)d_in[4];
    const float* bk = (const float*)d_in[5];
    const float* wv = (const float*)d_in[6];
    const float* bv = (const float*)d_in[7];
    const float* wo = (const float*)d_in[8];
    const float* bo = (const float*)d_in[9];
    const float* w1 = (const float*)d_in[10];
    const float* b1 = (const float*)d_in[11];
    const float* w2 = (const float*)d_in[12];
    const float* b2 = (const float*)d_in[13];
    float* out = (float*)d_out;

    // ---- workspace carve (bytes) ----
    char* base = (char*)d_ws;
    ushort_t* wqb  = (ushort_t*)(base);
    ushort_t* wkvb = (ushort_t*)(base + 524288);         // wk || wv stacked [1024][256]
    ushort_t* wob  = (ushort_t*)(base + 1048576);
    ushort_t* w1b  = (ushort_t*)(base + 1572864);
    ushort_t* w2b  = (ushort_t*)(base + 3670016);
    ushort_t* x_decT_b = (ushort_t*)(base + 5767168);    // 16.8 MB
    ushort_t* q_pre    = (ushort_t*)(base + 22544384);   // 16.8 MB -> xo_pre/xres
    ushort_t* kvT      = (ushort_t*)(base + 39321600);   // 67 MB fused k|v -> hT
    ushort_t* x_encT_b = (ushort_t*)(base + 106430464);  // 16.8 MB -> attn_outT
    ushort_t* winb     = (ushort_t*)(base + 123207680);  // 23.1 MB bf16 -> y_pre
    float*    partQ    = (float*)(base + 169345024);     // 1 MB
    float*    partKV   = (float*)(base + 170393600);     // 2 MB
    float*    qm       = (float*)(base + 172490752);     // 8 KB each
    float*    qr       = qm + 2048;
    float*    vm       = qr + 2048;
    float*    vrs      = vm + 2048;
    float*    bkv      = vrs + 2048;                     // 4 KB f32 bias stack
    ushort_t* attn_outT = x_encT_b;
    ushort_t* xo_pre   = q_pre;
    ushort_t* hT       = kvT;
    ushort_t* y_pre    = winb;

    dim3 blk(256);
    dim3 blk512(512);

    // 0. weights -> bf16 (wk/wv adjacent = stacked); bias stack
    Cvt6Args ca;
    ca.src[0] = wq; ca.src[1] = wk; ca.src[2] = wv;
    ca.src[3] = wo; ca.src[4] = w1; ca.src[5] = w2;
    ca.dst[0] = wqb; ca.dst[1] = wkvb; ca.dst[2] = wkvb + 131072;
    ca.dst[3] = wob; ca.dst[4] = w1b; ca.dst[5] = w2b;
    ca.n[0] = 262144; ca.n[1] = 131072; ca.n[2] = 131072;
    ca.n[3] = 262144; ca.n[4] = 1048576; ca.n[5] = 1048576;
    cvt6<<<dim3(1024, 6), blk, 0, stream>>>(ca);
    bias_stack<<<dim3(4), blk, 0, stream>>>(bk, bv, bkv);

    // 1. transpose inputs to [B][L][C] bf16
    tcvt<<<dim3(LDD / 64, CDIM / 64, NB), blk, 0, stream>>>(x_dec, x_decT_b, CDIM, LDD);
    tcvt<<<dim3(LEE / 64, CENC / 64, NB), blk, 0, stream>>>(x_enc, x_encT_b, CENC, LEE);

    const float QSCALE = 0.125f * 1.4426950408889634f;   // 1/sqrt(hd) * log2(e)

    // 2. q raw GEMM (stats only); 3. fused k|v GEMM (raw, stats)
    mgemm2<0,1><<<dim3(CDIM / 128, LDD / 128, NB), blk, 0, stream>>>(x_decT_b, wqb, bq, q_pre, partQ, LDD, CDIM, CDIM);
    mgemm2<0,1><<<dim3(KVS / 128, LEE / 128, NB), blk, 0, stream>>>(x_encT_b, wkvb, bkv, kvT, partKV, LEE, KVS, CENC);
    stats_finish<<<dim3(8), blk, 0, stream>>>(partQ, partKV, qm, qr, vm, vrs, QSCALE);

    // 4. windowed attention (q-norm folded in-kernel) + overlap-add
    attn_win_mfma32<<<dim3(NWIN * NHEAD * NB), blk512, 0, stream>>>(q_pre, kvT, qm, qr, vm, vrs, winb);
    attn_finalize<<<dim3(LDD / 64, NHEAD, NB), blk, 0, stream>>>(winb, attn_outT);

    // 5. xres = IN(attn_outT @ wo^T + bo) + x_decT
    mgemm2<0,1><<<dim3(CDIM / 128, LDD / 128, NB), blk, 0, stream>>>(attn_outT, wob, bo, xo_pre, partQ, LDD, CDIM, CDIM);
    cn_apply_v<1><<<dim3(LDD / 16, 1, NB), blk, 0, stream>>>(xo_pre, partQ, x_decT_b, xo_pre, LDD, LDD / 128);

    // 6. h = gelu(xres @ w1^T + b1)
    mgemm2<1,0><<<dim3(HDIM / 128, LDD / 128, NB), blk, 0, stream>>>(xo_pre, w1b, b1, hT, nullptr, LDD, HDIM, CDIM);

    // 7. y = IN(h @ w2^T + b2) + xres -> f32 [B][C][L]
    mgemm2<0,1><<<dim3(CDIM / 128, LDD / 128, NB), blk, 0, stream>>>(hT, w2b, b2, y_pre, partQ, LDD, CDIM, HDIM);
    cn_apply_t<<<dim3(CDIM / 64, LDD / 64, NB), blk, 0, stream>>>(y_pre, partQ, xo_pre, out, LDD, LDD / 128);

    (void)in_sizes; (void)n_in; (void)out_size; (void)ws_size;
}